// Round 1
// baseline (180.603 us; speedup 1.0000x reference)
//
#include <hip/hip_runtime.h>
#include <math.h>

// v7: wave-independent counted-vmcnt software pipeline (no __syncthreads).
//
// Evidence: dur 169.3us = 2 harness poison fills (61.8+61.0us, 400MiB each)
// + ~46.5us kernel. Kernel roofline: HBM 107MB ~17us, VALU ~10us, LDS ~5us
// -> stall-bound at 46us from the bulk-synchronous stage -> vmcnt(0)+barrier
// -> compute structure (3 phase-locked blocks/CU; HBM idles during compute).
// Changes vs v6:
//  (1) 4 lanes/sample (q=row parity, h=filter pair); batch = 16 samples.
//  (2) per-wave 2x6.4KB LDS double-buffer, 4 batches/wave, 7 gload_lds each;
//      pipeline STAGE(0,1); {vmcnt(7); compute(b); lgkmcnt(0); STAGE(b+2)}.
//      Counted vmcnt keeps the next batch's loads in flight under compute
//      (T3/T4); asm memory fences pin batch order for in-order vmcnt math.
//  (3) no block barrier at all -> 12 independent wave pipelines per CU.
//  (4) quad LDS layout: R-row reads 2-way bank alias (free) vs v6's 4-way.

typedef float v2f __attribute__((ext_vector_type(2)));

#define SREAD(x) __int_as_float(__builtin_amdgcn_readfirstlane(__float_as_int(x)))
#define WAITVM(N) asm volatile("s_waitcnt vmcnt(" #N ")" ::: "memory")
#define WAITLGKM0() asm volatile("s_waitcnt lgkmcnt(0)" ::: "memory")
#define MEMFENCE() asm volatile("" ::: "memory")

__device__ __forceinline__ float dpp_swap1_f(float x) {      // lane ^ 1
    return __int_as_float(__builtin_amdgcn_mov_dpp(__float_as_int(x), 0xB1, 0xF, 0xF, true));
}
__device__ __forceinline__ float dpp_swap2_f(float x) {      // lane ^ 2
    return __int_as_float(__builtin_amdgcn_mov_dpp(__float_as_int(x), 0x4E, 0xF, 0xF, true));
}
__device__ __forceinline__ unsigned dpp_swap1_u(unsigned x) {
    return (unsigned)__builtin_amdgcn_mov_dpp((int)x, 0xB1, 0xF, 0xF, true);
}
__device__ __forceinline__ unsigned dpp_swap2_u(unsigned x) {
    return (unsigned)__builtin_amdgcn_mov_dpp((int)x, 0x4E, 0xF, 0xF, true);
}

__device__ __forceinline__ void gload16(const float* g, float* l) {
    __builtin_amdgcn_global_load_lds(
        (const __attribute__((address_space(1))) void*)g,
        (__attribute__((address_space(3))) void*)l, 16, 0, 0);
}
__device__ __forceinline__ void gload4(const float* g, float* l) {
    __builtin_amdgcn_global_load_lds(
        (const __attribute__((address_space(1))) void*)g,
        (__attribute__((address_space(3))) void*)l, 4, 0, 0);
}

__global__ __launch_bounds__(128, 3) void CNN2D_37495064494620_kernel(
    const float* __restrict__ v,
    const float* __restrict__ cw,   // [4,1,3,3]
    const float* __restrict__ cb,   // [4]
    const float* __restrict__ dw,   // [4,1,2,2]
    const float* __restrict__ db,   // [1]
    float* __restrict__ out,        // [2*B]
    int B)
{
    const int lane = threadIdx.x & 63;
    const int w    = threadIdx.x >> 6;    // wave in block (0..1)
    const int q    = lane & 1;            // conv-row parity
    const int h    = (lane >> 1) & 1;     // filter-pair owner (f0,f1 | f2,f3)
    const int g    = lane >> 2;           // sample within batch (0..15)

    // per-wave: 2 buffers x 1600 floats (16 samples x 100)
    __shared__ __align__(16) float smraw[6400];
    float* sm = smraw + w * 3200;

    // ---- uniform weights -> SGPRs, then per-lane selected copies ----
    float Wf[4][9];
    #pragma unroll
    for (int f = 0; f < 4; ++f)
        #pragma unroll
        for (int t = 0; t < 9; ++t)
            Wf[f][t] = SREAD(cw[f * 9 + t]);
    // this lane's conv filter pair (2h, 2h+1), packed for v_pk_fma_f32
    v2f Wsel[9];
    #pragma unroll
    for (int t = 0; t < 9; ++t)
        Wsel[t] = (v2f){ h ? Wf[2][t] : Wf[0][t], h ? Wf[3][t] : Wf[1][t] };
    const float cb0 = SREAD(cb[0]), cb1 = SREAD(cb[1]);
    const float cb2 = SREAD(cb[2]), cb3 = SREAD(cb[3]);
    const v2f Cbsel = (v2f){ h ? cb2 : cb0, h ? cb3 : cb1 };

    float Dw4[4][4];
    #pragma unroll
    for (int f = 0; f < 4; ++f)
        #pragma unroll
        for (int t = 0; t < 4; ++t)
            Dw4[f][t] = SREAD(dw[f * 4 + t]);
    const float Db = SREAD(db[0]);
    // lane owns deconv tap kl = 2q + h; Dkl[f] = Dw[f][kl] via static selects
    float Dkl[4];
    #pragma unroll
    for (int f = 0; f < 4; ++f) {
        const float e01 = h ? Dw4[f][1] : Dw4[f][0];
        const float e23 = h ? Dw4[f][3] : Dw4[f][2];
        Dkl[f] = q ? e23 : e01;
    }
    // slots ordered: own pair (2h,2h+1) then partner pair (2-2h,3-2h)
    const float Ds0 = h ? Dkl[2] : Dkl[0];
    const float Ds1 = h ? Dkl[3] : Dkl[1];
    const float Ds2 = h ? Dkl[0] : Dkl[2];
    const float Ds3 = h ? Dkl[1] : Dkl[3];

    // All weight VMEM retired -> vmcnt baseline 0 for the counted pipeline.
    WAITVM(0);

    // wave's 64 samples: 4 batches x 16, contiguous in global memory
    const float* gbase = v + (size_t)blockIdx.x * 12800 + w * 6400;

    auto STAGE = [&](int b) {
        const float* gb = gbase + b * 1600;
        float* lb = sm + (b & 1) * 1600;
        #pragma unroll
        for (int k = 0; k < 6; ++k)
            gload16(gb + k * 256 + lane * 4, lb + k * 256);   // 1024B coalesced
        gload4(gb + 1536 + lane, lb + 1536);
    };

    STAGE(0);
    MEMFENCE();          // keep batch 0's 7 loads older than batch 1's
    STAGE(1);

    #pragma unroll 1
    for (int b = 0; b < 4; ++b) {
        // batch b ready when only the newest 7 loads (batch b+1) remain
        if (b < 3) WAITVM(7); else WAITVM(0);

        const float* my = sm + (b & 1) * 1600 + g * 100;
        unsigned sb = 0u;       // XOR of z sign bits (this lane's 25 taps)
        float l2 = 0.0f;        // sum of log2|z|

        #pragma unroll
        for (int i = 0; i < 5; ++i) {
            // conv row r1 = 2i+q; window rows r1-1, r1, r1+1 (wrap)
            const int r1 = 2 * i + q;
            const int r0 = (i == 0) ? (q ? 0 : 9) : (2 * i - 1 + q);
            const int r2 = (i == 4) ? (q ? 0 : 9) : (2 * i + 1 + q);

            float R[3][10];
            #pragma unroll
            for (int t = 0; t < 5; ++t) {
                float2 x0 = *(const float2*)(my + r0 * 10 + 2 * t);
                float2 x1 = *(const float2*)(my + r1 * 10 + 2 * t);
                float2 x2 = *(const float2*)(my + r2 * 10 + 2 * t);
                R[0][2 * t] = x0.x; R[0][2 * t + 1] = x0.y;
                R[1][2 * t] = x1.x; R[1][2 * t + 1] = x1.y;
                R[2][2 * t] = x2.x; R[2][2 * t + 1] = x2.y;
            }

            #pragma unroll
            for (int j = 0; j < 5; ++j) {
                // conv at cols 2j (a0) and 2j+1 (a1), this lane's filter pair
                v2f a0 = Cbsel, a1 = Cbsel;
                #pragma unroll
                for (int kr = 0; kr < 3; ++kr) {
                    #pragma unroll
                    for (int kc = 0; kc < 3; ++kc) {
                        const int cc0 = (2 * j + kc + 9) % 10;       // compile-time
                        const int cc1 = (2 * j + 1 + kc + 9) % 10;
                        const int t = kr * 3 + kc;
                        const v2f x0 = (v2f){R[kr][cc0], R[kr][cc0]};
                        const v2f x1 = (v2f){R[kr][cc1], R[kr][cc1]};
                        a0 = __builtin_elementwise_fma(x0, Wsel[t], a0);
                        a1 = __builtin_elementwise_fma(x1, Wsel[t], a1);
                    }
                }
                // 2x2 maxpool: dc-merge packed, then cross-q via DPP
                const v2f m = __builtin_elementwise_max(a0, a1);
                const float Px = fmaxf(m.x, dpp_swap1_f(m.x));
                const float Py = fmaxf(m.y, dpp_swap1_f(m.y));
                // partner filter pair's pooled values via cross-h DPP
                const float Qx = dpp_swap2_f(Px);
                const float Qy = dpp_swap2_f(Py);
                // deconv: this lane's single tap kl = 2q+h
                float z = Db;
                z = fmaf(Px, Ds0, z);
                z = fmaf(Py, Ds1, z);
                z = fmaf(Qx, Ds2, z);
                z = fmaf(Qy, Ds3, z);
                sb ^= __float_as_uint(z);
                l2 += __log2f(fabsf(z));
            }
        }

        // quad combine: each lane contributed 25 of the sample's 100 z's
        l2 += dpp_swap1_f(l2);
        l2 += dpp_swap2_f(l2);
        sb ^= dpp_swap1_u(sb);
        sb ^= dpp_swap2_u(sb);

        const int s = blockIdx.x * 128 + w * 64 + b * 16 + g;
        const int r = lane & 3;
        if (r == 0)      out[s]     = (sb & 0x80000000u) ? -1.0f : 1.0f;
        else if (r == 1) out[B + s] = l2 * 0.69314718055994531f;

        // Re-stage into the buffer just consumed. lgkmcnt(0) guarantees all
        // ds_reads of compute(b) drained before the direct-to-LDS writes of
        // batch b+2 can land (same buffer parity); the fence also stops the
        // scheduler from hoisting these loads into the compute region.
        if (b < 2) { WAITLGKM0(); STAGE(b + 2); }
    }
}

extern "C" void kernel_launch(void* const* d_in, const int* in_sizes, int n_in,
                              void* d_out, int out_size, void* d_ws, size_t ws_size,
                              hipStream_t stream) {
    const float* v  = (const float*)d_in[0];
    const float* cw = (const float*)d_in[1];
    const float* cb = (const float*)d_in[2];
    const float* dw = (const float*)d_in[3];
    const float* db = (const float*)d_in[4];
    float* out = (float*)d_out;

    const int B = in_sizes[0] / 100;       // 262144
    const int grid = B / 128;              // 128 samples per 128-thread block
    CNN2D_37495064494620_kernel<<<grid, 128, 0, stream>>>(v, cw, cb, dw, db, out, B);
}

// Round 2
// 169.364 us; speedup vs baseline: 1.0664x; 1.0664x over previous
//
#include <hip/hip_runtime.h>
#include <math.h>

// v8: restore TLP (8192 one-wave blocks), keep counted-vmcnt pipeline.
//
// Evidence from v7: kernel 65.6us, VALUBusy 39%, Occupancy 21%, HBM 13.8%.
// Total VALU issue time ~26us is invariant across v6/v7 -- v7 regressed
// purely on lost overlap (4096 waves = 4/SIMD of work; ~2 resident/SIMD).
// Changes vs v7:
//  (1) 64-thread blocks (1 wave), 32 samples/wave, 8192 blocks -> 8 waves/SIMD
//      of work; 12.8KB LDS/block -> up to 12 waves/CU resident.
//  (2) stage both 16-sample halves up front (14 gload_lds), WAITVM(7) ->
//      compute half 0 (hides half 1's HBM latency) -> WAITVM(0) -> half 1.
//      No barrier, no mid-loop restage.
//  (3) log-pairing (v6-validated): z-pair product -> 13 logs instead of 25
//      per lane-batch; sign via XOR of product sign bit.

typedef float v2f __attribute__((ext_vector_type(2)));

#define SREAD(x) __int_as_float(__builtin_amdgcn_readfirstlane(__float_as_int(x)))
#define WAITVM(N) asm volatile("s_waitcnt vmcnt(" #N ")" ::: "memory")
#define MEMFENCE() asm volatile("" ::: "memory")

__device__ __forceinline__ float dpp_swap1_f(float x) {      // lane ^ 1
    return __int_as_float(__builtin_amdgcn_mov_dpp(__float_as_int(x), 0xB1, 0xF, 0xF, true));
}
__device__ __forceinline__ float dpp_swap2_f(float x) {      // lane ^ 2
    return __int_as_float(__builtin_amdgcn_mov_dpp(__float_as_int(x), 0x4E, 0xF, 0xF, true));
}
__device__ __forceinline__ unsigned dpp_swap1_u(unsigned x) {
    return (unsigned)__builtin_amdgcn_mov_dpp((int)x, 0xB1, 0xF, 0xF, true);
}
__device__ __forceinline__ unsigned dpp_swap2_u(unsigned x) {
    return (unsigned)__builtin_amdgcn_mov_dpp((int)x, 0x4E, 0xF, 0xF, true);
}

__device__ __forceinline__ void gload16(const float* g, float* l) {
    __builtin_amdgcn_global_load_lds(
        (const __attribute__((address_space(1))) void*)g,
        (__attribute__((address_space(3))) void*)l, 16, 0, 0);
}
__device__ __forceinline__ void gload4(const float* g, float* l) {
    __builtin_amdgcn_global_load_lds(
        (const __attribute__((address_space(1))) void*)g,
        (__attribute__((address_space(3))) void*)l, 4, 0, 0);
}

__global__ __launch_bounds__(64, 4) void CNN2D_37495064494620_kernel(
    const float* __restrict__ v,
    const float* __restrict__ cw,   // [4,1,3,3]
    const float* __restrict__ cb,   // [4]
    const float* __restrict__ dw,   // [4,1,2,2]
    const float* __restrict__ db,   // [1]
    float* __restrict__ out,        // [2*B]
    int B)
{
    const int lane = threadIdx.x;         // one wave per block
    const int q    = lane & 1;            // conv-row parity
    const int h    = (lane >> 1) & 1;     // filter-pair owner (f0,f1 | f2,f3)
    const int g    = lane >> 2;           // sample within 16-sample batch

    __shared__ __align__(16) float sm[3200];   // 2 batches x 16 samples x 100

    // ---- uniform weights -> SGPRs, then per-lane selected copies ----
    float Wf[4][9];
    #pragma unroll
    for (int f = 0; f < 4; ++f)
        #pragma unroll
        for (int t = 0; t < 9; ++t)
            Wf[f][t] = SREAD(cw[f * 9 + t]);
    v2f Wsel[9];
    #pragma unroll
    for (int t = 0; t < 9; ++t)
        Wsel[t] = (v2f){ h ? Wf[2][t] : Wf[0][t], h ? Wf[3][t] : Wf[1][t] };
    const float cb0 = SREAD(cb[0]), cb1 = SREAD(cb[1]);
    const float cb2 = SREAD(cb[2]), cb3 = SREAD(cb[3]);
    const v2f Cbsel = (v2f){ h ? cb2 : cb0, h ? cb3 : cb1 };

    float Dw4[4][4];
    #pragma unroll
    for (int f = 0; f < 4; ++f)
        #pragma unroll
        for (int t = 0; t < 4; ++t)
            Dw4[f][t] = SREAD(dw[f * 4 + t]);
    const float Db = SREAD(db[0]);
    // lane owns deconv tap kl = 2q + h
    float Dkl[4];
    #pragma unroll
    for (int f = 0; f < 4; ++f) {
        const float e01 = h ? Dw4[f][1] : Dw4[f][0];
        const float e23 = h ? Dw4[f][3] : Dw4[f][2];
        Dkl[f] = q ? e23 : e01;
    }
    // slots ordered: own filter pair (2h,2h+1) then partner pair
    const float Ds0 = h ? Dkl[2] : Dkl[0];
    const float Ds1 = h ? Dkl[3] : Dkl[1];
    const float Ds2 = h ? Dkl[0] : Dkl[2];
    const float Ds3 = h ? Dkl[1] : Dkl[3];

    // Weight VMEM retired -> vmcnt baseline 0 for counted waits below.
    WAITVM(0);

    // wave's 32 samples: 2 batches x 16, contiguous in global memory
    const float* gbase = v + (size_t)blockIdx.x * 3200;

    // STAGE(b): 16 samples = 6400B = 6x(64 lanes x 16B) + 1x(64 lanes x 4B)
    auto STAGE = [&](int b) {
        const float* gb = gbase + b * 1600;
        float* lb = sm + b * 1600;
        #pragma unroll
        for (int k = 0; k < 6; ++k)
            gload16(gb + k * 256 + lane * 4, lb + k * 256);
        gload4(gb + 1536 + lane, lb + 1536);
    };

    auto COMPUTE = [&](const float* buf, int sbase) {
        const float* my = buf + g * 100;
        unsigned sb = 0u;       // XOR of z sign bits (this lane's 25 taps)
        float l2 = 0.0f;        // sum of log2|z|
        float zpend = 0.0f;     // pending z for log-pairing

        #pragma unroll
        for (int i = 0; i < 5; ++i) {
            // conv row r1 = 2i+q; window rows r1-1, r1, r1+1 (wrap)
            const int r1 = 2 * i + q;
            const int r0 = (i == 0) ? (q ? 0 : 9) : (2 * i - 1 + q);
            const int r2 = (i == 4) ? (q ? 0 : 9) : (2 * i + 1 + q);

            float R[3][10];
            #pragma unroll
            for (int t = 0; t < 5; ++t) {
                float2 x0 = *(const float2*)(my + r0 * 10 + 2 * t);
                float2 x1 = *(const float2*)(my + r1 * 10 + 2 * t);
                float2 x2 = *(const float2*)(my + r2 * 10 + 2 * t);
                R[0][2 * t] = x0.x; R[0][2 * t + 1] = x0.y;
                R[1][2 * t] = x1.x; R[1][2 * t + 1] = x1.y;
                R[2][2 * t] = x2.x; R[2][2 * t + 1] = x2.y;
            }

            #pragma unroll
            for (int j = 0; j < 5; ++j) {
                // conv at cols 2j (a0) and 2j+1 (a1), this lane's filter pair
                v2f a0 = Cbsel, a1 = Cbsel;
                #pragma unroll
                for (int kr = 0; kr < 3; ++kr) {
                    #pragma unroll
                    for (int kc = 0; kc < 3; ++kc) {
                        const int cc0 = (2 * j + kc + 9) % 10;       // compile-time
                        const int cc1 = (2 * j + 1 + kc + 9) % 10;
                        const int t = kr * 3 + kc;
                        const v2f x0 = (v2f){R[kr][cc0], R[kr][cc0]};
                        const v2f x1 = (v2f){R[kr][cc1], R[kr][cc1]};
                        a0 = __builtin_elementwise_fma(x0, Wsel[t], a0);
                        a1 = __builtin_elementwise_fma(x1, Wsel[t], a1);
                    }
                }
                // 2x2 maxpool: dc-merge packed, then cross-q via DPP
                const v2f m = __builtin_elementwise_max(a0, a1);
                const float Px = fmaxf(m.x, dpp_swap1_f(m.x));
                const float Py = fmaxf(m.y, dpp_swap1_f(m.y));
                // partner filter pair's pooled values via cross-h DPP
                const float Qx = dpp_swap2_f(Px);
                const float Qy = dpp_swap2_f(Py);
                // deconv: this lane's single tap kl = 2q+h
                float z = Db;
                z = fmaf(Px, Ds0, z);
                z = fmaf(Py, Ds1, z);
                z = fmaf(Qx, Ds2, z);
                z = fmaf(Qy, Ds3, z);

                // log-pairing: product of consecutive z's -> one log per pair
                const int pos = i * 5 + j;     // compile-time after unroll
                if (pos == 24) {
                    sb ^= __float_as_uint(z);
                    l2 += __log2f(fabsf(z));
                } else if (pos & 1) {
                    const float zp = zpend * z;
                    sb ^= __float_as_uint(zp);
                    l2 += __log2f(fabsf(zp));
                } else {
                    zpend = z;
                }
            }
        }

        // quad combine: each lane contributed 25 of the sample's 100 z's
        l2 += dpp_swap1_f(l2);
        l2 += dpp_swap2_f(l2);
        sb ^= dpp_swap1_u(sb);
        sb ^= dpp_swap2_u(sb);

        const int s = sbase + g;
        const int r = lane & 3;
        if (r == 0)      out[s]     = (sb & 0x80000000u) ? -1.0f : 1.0f;
        else if (r == 1) out[B + s] = l2 * 0.69314718055994531f;
    };

    STAGE(0);
    MEMFENCE();          // pin issue order: batch 0's 7 loads oldest
    STAGE(1);

    const int sb0 = blockIdx.x * 32;
    WAITVM(7);           // batch 0 landed; batch 1's 7 still in flight
    COMPUTE(sm, sb0);
    WAITVM(0);           // batch 1 landed (covered by batch 0 compute)
    COMPUTE(sm + 1600, sb0 + 16);
}

extern "C" void kernel_launch(void* const* d_in, const int* in_sizes, int n_in,
                              void* d_out, int out_size, void* d_ws, size_t ws_size,
                              hipStream_t stream) {
    const float* v  = (const float*)d_in[0];
    const float* cw = (const float*)d_in[1];
    const float* cb = (const float*)d_in[2];
    const float* dw = (const float*)d_in[3];
    const float* db = (const float*)d_in[4];
    float* out = (float*)d_out;

    const int B = in_sizes[0] / 100;       // 262144
    const int grid = B / 32;               // 32 samples per one-wave block
    CNN2D_37495064494620_kernel<<<grid, 64, 0, stream>>>(v, cw, cb, dw, db, out, B);
}